// Round 1
// baseline (713.960 us; speedup 1.0000x reference)
//
#include <hip/hip_runtime.h>
#include <cstddef>

#define B_    512
#define IN_   1023
#define INP1  1024
#define OUT_  512
#define OUT4  128     // OUT_/4
#define CLIPV 2.0f
#define LNEPS 1e-5f

// block-wide reduction of two floats (sum). blockDim.x must be multiple of 64.
__device__ __forceinline__ float2 block_reduce2(float a, float b, float2* lds) {
    #pragma unroll
    for (int off = 32; off; off >>= 1) {
        a += __shfl_down(a, off, 64);
        b += __shfl_down(b, off, 64);
    }
    const int lane = threadIdx.x & 63;
    const int wid  = threadIdx.x >> 6;
    const int nw   = blockDim.x >> 6;
    if (lane == 0) lds[wid] = make_float2(a, b);
    __syncthreads();
    if (wid == 0) {
        float2 v = (lane < nw) ? lds[lane] : make_float2(0.f, 0.f);
        a = v.x; b = v.y;
        #pragma unroll
        for (int off = 8; off; off >>= 1) {
            a += __shfl_down(a, off, 64);
            b += __shfl_down(b, off, 64);
        }
        if (lane == 0) lds[0] = make_float2(a, b);
    }
    __syncthreads();
    float2 r = lds[0];
    __syncthreads();   // make lds reusable by caller
    return r;
}

// One block (1024 threads = 16 waves) per sample b.
// Threads arranged as (chunk 0..7) x (o4 0..127). Each chunk-group streams
// 128 rows of hebb/weight/alpha (float4-coalesced), accumulating y_pre.
__global__ __launch_bounds__(1024) void k1_ypre_ln_mod(
    const float* __restrict__ x, const float* __restrict__ hebb,
    const float* __restrict__ weight, const float* __restrict__ alpha,
    const float* __restrict__ ln_g, const float* __restrict__ ln_b,
    const float* __restrict__ mod_w, const float* __restrict__ mod_b,
    float* __restrict__ y_out, float* __restrict__ m_out)
{
    const int b     = blockIdx.x;
    const int tid   = threadIdx.x;
    const int o4    = tid & 127;
    const int chunk = tid >> 7;          // 0..7

    const float4* __restrict__ h4 = (const float4*)hebb + (size_t)b * (INP1 * OUT4);
    const float4* __restrict__ w4 = (const float4*)weight;
    const float4* __restrict__ a4 = (const float4*)alpha;
    const float*  __restrict__ xr = x + (size_t)b * IN_;

    float4 acc = make_float4(0.f, 0.f, 0.f, 0.f);
    const int i0 = chunk * 128;
    #pragma unroll 4
    for (int k = 0; k < 128; ++k) {
        const int i = i0 + k;
        const float xv = (i < IN_) ? xr[i] : 1.0f;   // bias column of ones
        const float4 h = h4[(size_t)i * OUT4 + o4];
        const float4 w = w4[i * OUT4 + o4];
        const float4 a = a4[i * OUT4 + o4];
        acc.x = fmaf(xv, fmaf(a.x, h.x, w.x), acc.x);
        acc.y = fmaf(xv, fmaf(a.y, h.y, w.y), acc.y);
        acc.z = fmaf(xv, fmaf(a.z, h.z, w.z), acc.z);
        acc.w = fmaf(xv, fmaf(a.w, h.w, w.w), acc.w);
    }

    __shared__ float  part[8][OUT_];     // 16 KiB
    __shared__ float2 rbuf[16];
    ((float4*)part[chunk])[o4] = acc;
    __syncthreads();

    // reduce 8 chunk-partials: thread tid<512 owns output column o = tid
    const int o = tid;
    float ypre = 0.f;
    if (tid < OUT_) {
        #pragma unroll
        for (int c = 0; c < 8; ++c) ypre += part[c][o];
    }

    // LayerNorm over OUT_ values
    const float va = (tid < OUT_) ? ypre : 0.f;
    float2 ss = block_reduce2(va, va * va, rbuf);
    const float mu   = ss.x * (1.0f / OUT_);
    const float var  = ss.y * (1.0f / OUT_) - mu * mu;
    const float rstd = rsqrtf(var + LNEPS);

    float yv = 0.f;
    if (tid < OUT_) {
        yv = tanhf(fmaf(ln_g[o], (ypre - mu) * rstd, ln_b[o]));
        y_out[(size_t)b * OUT_ + o] = yv;
    }

    // modulator scalar m[b] = tanh(sum_o y*mod_w[o] + mod_b)
    float2 ms = block_reduce2((tid < OUT_) ? yv * mod_w[o] : 0.f, 0.f, rbuf);
    if (tid == 0) m_out[b] = tanhf(ms.x + mod_b[0]);
}

// hebb_new = clip(hebb + (m*fan_w + fan_b) * xp * y, +-CLIP), float4 grid-stride
__global__ __launch_bounds__(256) void k2_hebb_update(
    const float* __restrict__ x, const float* __restrict__ hebb,
    const float* __restrict__ y, const float* __restrict__ m,
    const float* __restrict__ fan_w, const float* __restrict__ fan_b,
    float* __restrict__ hebb_out)
{
    const size_t total4 = (size_t)B_ * INP1 * OUT4;   // 67,108,864
    const size_t stride = (size_t)gridDim.x * blockDim.x;
    for (size_t idx = (size_t)blockIdx.x * blockDim.x + threadIdx.x;
         idx < total4; idx += stride) {
        const int o4 = (int)(idx & (OUT4 - 1));
        const int i  = (int)((idx >> 7) & (INP1 - 1));
        const int b  = (int)(idx >> 17);

        const float xv = (i < IN_) ? x[(size_t)b * IN_ + i] : 1.0f;
        const float mb = m[b];
        const float4 h  = ((const float4*)hebb)[idx];
        const float4 yv = ((const float4*)y)[(size_t)b * OUT4 + o4];
        const float4 fw = ((const float4*)fan_w)[o4];
        const float4 fb = ((const float4*)fan_b)[o4];

        float4 r;
        r.x = fminf(fmaxf(fmaf(fmaf(mb, fw.x, fb.x) * xv, yv.x, h.x), -CLIPV), CLIPV);
        r.y = fminf(fmaxf(fmaf(fmaf(mb, fw.y, fb.y) * xv, yv.y, h.y), -CLIPV), CLIPV);
        r.z = fminf(fmaxf(fmaf(fmaf(mb, fw.z, fb.z) * xv, yv.z, h.z), -CLIPV), CLIPV);
        r.w = fminf(fmaxf(fmaf(fmaf(mb, fw.w, fb.w) * xv, yv.w, h.w), -CLIPV), CLIPV);
        ((float4*)hebb_out)[idx] = r;
    }
}

extern "C" void kernel_launch(void* const* d_in, const int* in_sizes, int n_in,
                              void* d_out, int out_size, void* d_ws, size_t ws_size,
                              hipStream_t stream) {
    const float* x      = (const float*)d_in[0];
    const float* hebb   = (const float*)d_in[1];
    const float* weight = (const float*)d_in[2];
    const float* alpha  = (const float*)d_in[3];
    const float* ln_g   = (const float*)d_in[4];
    const float* ln_b   = (const float*)d_in[5];
    const float* mod_w  = (const float*)d_in[6];
    const float* mod_b  = (const float*)d_in[7];
    const float* fan_w  = (const float*)d_in[8];
    const float* fan_b  = (const float*)d_in[9];

    float* out      = (float*)d_out;
    float* y_out    = out;                               // [B, OUT]
    float* m_out    = out + (size_t)B_ * OUT_;           // [B, 1]
    float* hebb_out = m_out + B_;                        // [B, IN+1, OUT]

    k1_ypre_ln_mod<<<B_, 1024, 0, stream>>>(x, hebb, weight, alpha,
                                            ln_g, ln_b, mod_w, mod_b,
                                            y_out, m_out);

    k2_hebb_update<<<8192, 256, 0, stream>>>(x, hebb, y_out, m_out,
                                             fan_w, fan_b, hebb_out);
}

// Round 3
// 648.777 us; speedup vs baseline: 1.1005x; 1.1005x over previous
//
#include <hip/hip_runtime.h>
#include <cstddef>

#define B_       512
#define IN_      1023
#define INP1     1024
#define OUT_     512
#define OUT4     128      // OUT_/4
#define CLIPV    2.0f
#define LNEPS    1e-5f
#define SLABS    4        // i-slabs per sample
#define SLABROWS 256      // INP1/SLABS

typedef float fx4 __attribute__((ext_vector_type(4)));   // nontemporal-friendly

// block-wide sum-reduction of two floats. blockDim.x multiple of 64, <=1024.
__device__ __forceinline__ float2 block_reduce2(float a, float b, float2* lds) {
    #pragma unroll
    for (int off = 32; off; off >>= 1) {
        a += __shfl_down(a, off, 64);
        b += __shfl_down(b, off, 64);
    }
    const int lane = threadIdx.x & 63;
    const int wid  = threadIdx.x >> 6;
    const int nw   = blockDim.x >> 6;
    if (lane == 0) lds[wid] = make_float2(a, b);
    __syncthreads();
    if (wid == 0) {
        float2 v = (lane < nw) ? lds[lane] : make_float2(0.f, 0.f);
        a = v.x; b = v.y;
        #pragma unroll
        for (int off = 8; off; off >>= 1) {
            a += __shfl_down(a, off, 64);
            b += __shfl_down(b, off, 64);
        }
        if (lane == 0) lds[0] = make_float2(a, b);
    }
    __syncthreads();
    float2 r = lds[0];
    __syncthreads();
    return r;
}

// k1a: partial y_pre per (sample b, i-slab s). 2048 blocks x 256 threads.
// Inner loop: 3 coalesced float4 loads (hebb HBM; weight/alpha L2-hot).
__global__ __launch_bounds__(256) void k1a_partial(
    const float* __restrict__ x, const float* __restrict__ hebb,
    const float* __restrict__ weight, const float* __restrict__ alpha,
    float* __restrict__ ws_part)
{
    const int bs   = blockIdx.x;        // b*SLABS + s
    const int b    = bs >> 2;
    const int s    = bs & 3;
    const int tid  = threadIdx.x;
    const int o4   = tid & 127;
    const int half = tid >> 7;          // 0..1

    __shared__ float  xs[SLABROWS];
    __shared__ float4 part[2][OUT4];

    {
        const int i = s * SLABROWS + tid;
        xs[tid] = (i < IN_) ? x[(size_t)b * IN_ + i] : 1.0f;  // bias row = 1
    }
    __syncthreads();

    const int i0 = s * SLABROWS + half * 128;
    const float4* __restrict__ h4 = (const float4*)hebb  + ((size_t)b * INP1 + i0) * OUT4 + o4;
    const float4* __restrict__ w4 = (const float4*)weight + (size_t)i0 * OUT4 + o4;
    const float4* __restrict__ a4 = (const float4*)alpha  + (size_t)i0 * OUT4 + o4;
    const float* __restrict__ xk = xs + half * 128;

    float4 acc = make_float4(0.f, 0.f, 0.f, 0.f);
    #pragma unroll 4
    for (int k = 0; k < 128; ++k) {
        const float  xv = xk[k];
        const float4 h  = h4[(size_t)k * OUT4];
        const float4 w  = w4[(size_t)k * OUT4];
        const float4 a  = a4[(size_t)k * OUT4];
        acc.x = fmaf(xv, fmaf(a.x, h.x, w.x), acc.x);
        acc.y = fmaf(xv, fmaf(a.y, h.y, w.y), acc.y);
        acc.z = fmaf(xv, fmaf(a.z, h.z, w.z), acc.z);
        acc.w = fmaf(xv, fmaf(a.w, h.w, w.w), acc.w);
    }

    part[half][o4] = acc;
    __syncthreads();
    if (half == 0) {
        float4 p = part[0][o4];
        const float4 q = part[1][o4];
        p.x += q.x; p.y += q.y; p.z += q.z; p.w += q.w;
        ((float4*)ws_part)[(size_t)bs * OUT4 + o4] = p;
    }
}

// k1b: reduce SLABS partials -> LayerNorm -> tanh -> y, m. 512 blocks x 512 thr.
__global__ __launch_bounds__(512) void k1b_ln_mod(
    const float* __restrict__ ws_part,
    const float* __restrict__ ln_g, const float* __restrict__ ln_b,
    const float* __restrict__ mod_w, const float* __restrict__ mod_b,
    float* __restrict__ y_out, float* __restrict__ m_out)
{
    const int b = blockIdx.x;
    const int o = threadIdx.x;
    __shared__ float2 rbuf[16];

    float ypre = 0.f;
    #pragma unroll
    for (int s = 0; s < SLABS; ++s)
        ypre += ws_part[((size_t)b * SLABS + s) * OUT_ + o];

    float2 ss = block_reduce2(ypre, ypre * ypre, rbuf);
    const float mu   = ss.x * (1.0f / OUT_);
    const float var  = ss.y * (1.0f / OUT_) - mu * mu;
    const float rstd = rsqrtf(var + LNEPS);

    const float yv = tanhf(fmaf(ln_g[o], (ypre - mu) * rstd, ln_b[o]));
    y_out[(size_t)b * OUT_ + o] = yv;

    float2 ms = block_reduce2(yv * mod_w[o], 0.f, rbuf);
    if (o == 0) m_out[b] = tanhf(ms.x + mod_b[0]);
}

// k2: hebb_new = clip(hebb + coef_o * x_i, +-CLIP) with coef_o = (m*fw_o+fb_o)*y_o.
// One block per (b, i-slab), REVERSED so it starts on the L3-resident tail of
// hebb left by k1a. Inner loop: 1 float4 load + 1 nontemporal float4 store.
__global__ __launch_bounds__(256) void k2_update(
    const float* __restrict__ x, const float* __restrict__ hebb,
    const float* __restrict__ y, const float* __restrict__ m,
    const float* __restrict__ fan_w, const float* __restrict__ fan_b,
    float* __restrict__ hebb_out)
{
    const int bsr  = (int)gridDim.x - 1 - (int)blockIdx.x;   // reverse order
    const int b    = bsr >> 2;
    const int s    = bsr & 3;
    const int tid  = threadIdx.x;
    const int o4   = tid & 127;
    const int half = tid >> 7;

    __shared__ float xs[SLABROWS];
    {
        const int i = s * SLABROWS + tid;
        xs[tid] = (i < IN_) ? x[(size_t)b * IN_ + i] : 1.0f;
    }
    __syncthreads();

    const float  mb = m[b];
    const float4 yv = ((const float4*)y)[(size_t)b * OUT4 + o4];
    const float4 fw = ((const float4*)fan_w)[o4];
    const float4 fb = ((const float4*)fan_b)[o4];
    float4 coef;
    coef.x = fmaf(mb, fw.x, fb.x) * yv.x;
    coef.y = fmaf(mb, fw.y, fb.y) * yv.y;
    coef.z = fmaf(mb, fw.z, fb.z) * yv.z;
    coef.w = fmaf(mb, fw.w, fb.w) * yv.w;

    const int i0 = s * SLABROWS + half * 128;
    const size_t base = ((size_t)b * INP1 + i0) * OUT4 + o4;
    const fx4* __restrict__ h4  = (const fx4*)hebb + base;
    fx4* __restrict__       ho4 = (fx4*)hebb_out + base;
    const float* __restrict__ xk = xs + half * 128;

    #pragma unroll 4
    for (int k = 0; k < 128; ++k) {
        const float xv = xk[k];
        const fx4   h  = h4[(size_t)k * OUT4];
        fx4 r;
        r.x = fminf(fmaxf(fmaf(coef.x, xv, h.x), -CLIPV), CLIPV);
        r.y = fminf(fmaxf(fmaf(coef.y, xv, h.y), -CLIPV), CLIPV);
        r.z = fminf(fmaxf(fmaf(coef.z, xv, h.z), -CLIPV), CLIPV);
        r.w = fminf(fmaxf(fmaf(coef.w, xv, h.w), -CLIPV), CLIPV);
        __builtin_nontemporal_store(r, &ho4[(size_t)k * OUT4]);
    }
}

extern "C" void kernel_launch(void* const* d_in, const int* in_sizes, int n_in,
                              void* d_out, int out_size, void* d_ws, size_t ws_size,
                              hipStream_t stream) {
    const float* x      = (const float*)d_in[0];
    const float* hebb   = (const float*)d_in[1];
    const float* weight = (const float*)d_in[2];
    const float* alpha  = (const float*)d_in[3];
    const float* ln_g   = (const float*)d_in[4];
    const float* ln_b   = (const float*)d_in[5];
    const float* mod_w  = (const float*)d_in[6];
    const float* mod_b  = (const float*)d_in[7];
    const float* fan_w  = (const float*)d_in[8];
    const float* fan_b  = (const float*)d_in[9];

    float* out      = (float*)d_out;
    float* y_out    = out;                               // [B, OUT]
    float* m_out    = out + (size_t)B_ * OUT_;           // [B]
    float* hebb_out = m_out + B_;                        // [B, IN+1, OUT]

    // partial-sum scratch: B*SLABS*OUT floats = 4 MiB
    const size_t part_bytes = (size_t)B_ * SLABS * OUT_ * sizeof(float);
    float* ws_part = (ws_size >= part_bytes) ? (float*)d_ws
                                             : hebb_out;  // safe: consumed by k1b
                                                          // before k2 overwrites

    k1a_partial<<<B_ * SLABS, 256, 0, stream>>>(x, hebb, weight, alpha, ws_part);
    k1b_ln_mod<<<B_, OUT_, 0, stream>>>(ws_part, ln_g, ln_b, mod_w, mod_b,
                                        y_out, m_out);
    k2_update<<<B_ * SLABS, 256, 0, stream>>>(x, hebb, y_out, m_out,
                                              fan_w, fan_b, hebb_out);
}